// Round 4
// baseline (178.862 us; speedup 1.0000x reference)
//
#include <hip/hip_runtime.h>

constexpr int T_TOK = 8192;
constexpr int H_DIM = 2048;
constexpr int E_NUM = 8;
constexpr int L_DIM = 16;

constexpr int NSB   = 8;     // h-slabs of 256
constexpr int NBLK2 = 8;     // sinkhorn blocks
constexpr int BLK2  = 1024;  // sinkhorn threads/block; NBLK2*BLK2 == T_TOK

// workspace layout (float offsets); slab first (8B aligned at 0)
constexpr size_t WS_SLAB = 0;                      // 2*NBLK2*16 u64 = 512 floats
constexpr size_t WS_PB   = 512;                    // NSB * T * 16 floats

// ---------------- Kernel 1: grouped logits partials ----------------
// 1024 blocks = (tset 0..127)<<3 | (sb 0..7); block = 64 tokens x 256 h.
// quad of lanes: 4 lanes x 4 h-chunks, 4 tokens per lane (acc[4][16]) ->
// 16 FMA per ds_read_b128 (was 4), and 4 lanes share one 64B x line.
__global__ __launch_bounds__(256, 4) void k1a(const float* __restrict__ x,
                                              const float* __restrict__ w1,
                                              const int* __restrict__ tpe,
                                              float* __restrict__ pb) {
    const int tid  = threadIdx.x;
    const int sb   = blockIdx.x & 7;
    const int tset = blockIdx.x >> 3;
    const int wvi  = tid >> 6;          // wave 0..3 -> h sub-window
    const int lane = tid & 63;
    const int quad = lane >> 2;         // 0..15
    const int a    = lane & 3;          // h-chunk phase within quad
    const int h0   = sb * 256;

    // union LDS: phase 1 = wT[16 l][260] (4160 f); phase 2 = red[4*64][17] (4352 f)
    __shared__ float smem[4352];

    // expert id (block's 64 tokens lie in one expert group: boundaries at 1024)
    int e = 0;
    {
        const int tok0 = tset * 64;
        int accum = 0;
        #pragma unroll
        for (int i = 0; i < E_NUM - 1; ++i) {
            accum += tpe[i];
            e += (tok0 >= accum) ? 1 : 0;
        }
    }
    const int e0 = __builtin_amdgcn_readfirstlane(e);

    // ---- stage w[e][h0..h0+256)[16] transposed -> wT[l][h], stride 260 ----
    {
        const float4* wsrc =
            reinterpret_cast<const float4*>(w1 + ((size_t)e0 * H_DIM + h0) * L_DIM);
        #pragma unroll
        for (int itr = 0; itr < 4; ++itr) {
            const int idx = itr * 256 + tid;     // float4 id 0..1023
            const float4 v = wsrc[idx];          // w[h][l0..l0+3]
            const int h  = idx >> 2;
            const int l0 = (idx & 3) * 4;
            smem[(l0 + 0) * 260 + h] = v.x;      // banks: 2-way alias only (free)
            smem[(l0 + 1) * 260 + h] = v.y;
            smem[(l0 + 2) * 260 + h] = v.z;
            smem[(l0 + 3) * 260 + h] = v.w;
        }
    }

    // x float4 base for (token = tset*64 + r*16 + quad, chunk = a + 4k)
    const float4* __restrict__ x4 = reinterpret_cast<const float4*>(x);
    const size_t xbase = (size_t)(tset * 64 + quad) * (H_DIM / 4) + (size_t)(h0 + wvi * 64) / 4;

    float acc[4][16];
    #pragma unroll
    for (int r = 0; r < 4; ++r)
        #pragma unroll
        for (int l = 0; l < 16; ++l) acc[r][l] = 0.f;

    // k=0 x loads in flight before the barrier
    float4 xk[4], xn[4];
    #pragma unroll
    for (int r = 0; r < 4; ++r)
        xk[r] = x4[xbase + (size_t)r * 16 * (H_DIM / 4) + a];

    __syncthreads();   // wT ready

    #pragma unroll
    for (int k = 0; k < 4; ++k) {
        if (k < 3) {
            #pragma unroll
            for (int r = 0; r < 4; ++r)
                xn[r] = x4[xbase + (size_t)r * 16 * (H_DIM / 4) + a + 4 * (k + 1)];
        }
        const int c4 = wvi * 64 + (a + 4 * k) * 4;   // float offset in wT row
        #pragma unroll
        for (int l = 0; l < 16; ++l) {
            // 4 distinct addrs (a=0..3) x 16-quad broadcast: conflict-free
            const float4 w4 = *reinterpret_cast<const float4*>(&smem[l * 260 + c4]);
            #pragma unroll
            for (int r = 0; r < 4; ++r)
                acc[r][l] += xk[r].x * w4.x + xk[r].y * w4.y
                           + xk[r].z * w4.z + xk[r].w * w4.w;
        }
        #pragma unroll
        for (int r = 0; r < 4; ++r) xk[r] = xn[r];
    }

    // quad reduce across a (deterministic xor nesting)
    #pragma unroll
    for (int m = 1; m <= 2; m <<= 1) {
        #pragma unroll
        for (int r = 0; r < 4; ++r)
            #pragma unroll
            for (int l = 0; l < 16; ++l)
                acc[r][l] += __shfl_xor(acc[r][l], m, 64);
    }

    __syncthreads();   // done reading wT; reuse smem as red[wv*64+tok][17]
    #pragma unroll
    for (int r = 0; r < 4; ++r) {
        const int tok = r * 16 + quad;
        #pragma unroll
        for (int j = 0; j < 4; ++j)
            smem[(wvi * 64 + tok) * 17 + a * 4 + j] = acc[r][a * 4 + j];
    }
    __syncthreads();

    // 64 tok * 16 l = 1024 outputs; coalesced store
    #pragma unroll
    for (int i = 0; i < 4; ++i) {
        const int p   = i * 256 + tid;
        const int tok = p >> 4;
        const int l   = p & 15;
        const float s = smem[(0 * 64 + tok) * 17 + l] + smem[(1 * 64 + tok) * 17 + l]
                      + smem[(2 * 64 + tok) * 17 + l] + smem[(3 * 64 + tok) * 17 + l];
        pb[(size_t)sb * (T_TOK * L_DIM) + (size_t)tset * 1024 + p] = s;
    }
}

// ---------------- Kernel 2: Sinkhorn + fused finalize ----------------
// 8 blocks x 1024 thr (one row/thread, c[16] in VGPRs). One-sided sync:
// per iteration each block publishes 16 col-partials as {tag,f32} u64
// relaxed agent-atomics (parity double-buffered); 128 threads spin, one
// entry each. write(it+1) implies read(it) done, so 2-ahead overwrite is
// impossible. Deterministic: fixed-order sums, bitwise-stable replays.
__global__ __launch_bounds__(1024) void k_sinkhorn(float* __restrict__ ws,
                                                   float* __restrict__ out) {
    unsigned long long* slab = reinterpret_cast<unsigned long long*>(ws + WS_SLAB);
    const float* pb = ws + WS_PB;

    const int tid  = threadIdx.x;
    const int t    = blockIdx.x * BLK2 + tid;   // row id
    const int wv   = tid >> 6;                  // 0..15
    const int lane = tid & 63;

    // fused: sum the 8 h-slab partials, exp -> c[]
    float c[16];
    {
        float4 a0 = {0,0,0,0}, a1 = {0,0,0,0}, a2 = {0,0,0,0}, a3 = {0,0,0,0};
        #pragma unroll
        for (int b = 0; b < NSB; ++b) {
            const float4* pr =
                reinterpret_cast<const float4*>(pb + (size_t)b * (T_TOK * L_DIM) + (size_t)t * 16);
            const float4 p0 = pr[0], p1 = pr[1], p2 = pr[2], p3 = pr[3];
            a0.x += p0.x; a0.y += p0.y; a0.z += p0.z; a0.w += p0.w;
            a1.x += p1.x; a1.y += p1.y; a1.z += p1.z; a1.w += p1.w;
            a2.x += p2.x; a2.y += p2.y; a2.z += p2.z; a2.w += p2.w;
            a3.x += p3.x; a3.y += p3.y; a3.z += p3.z; a3.w += p3.w;
        }
        const float sv[16] = {a0.x, a0.y, a0.z, a0.w, a1.x, a1.y, a1.z, a1.w,
                              a2.x, a2.y, a2.z, a2.w, a3.x, a3.y, a3.z, a3.w};
        #pragma unroll
        for (int l = 0; l < 16; ++l) c[l] = expf(sv[l]);
    }

    float d1[16];
    #pragma unroll
    for (int l = 0; l < 16; ++l) d1[l] = 1.f;

    __shared__ float s_wpart[16][16];
    __shared__ float s_bpart[NBLK2][16];
    __shared__ float s_d1n[16];

    float d0n = 0.f;
    float err = 1e9f;
    int it = 0;

    do {
        float s = 0.f;
        #pragma unroll
        for (int l = 0; l < 16; ++l) s += c[l] * d1[l];
        d0n = (1.f / (float)T_TOK) / (s + 1e-8f);

        float con[16];
        #pragma unroll
        for (int l = 0; l < 16; ++l) con[l] = d0n * c[l];
        #pragma unroll
        for (int m = 1; m < 64; m <<= 1) {
            #pragma unroll
            for (int l = 0; l < 16; ++l) con[l] += __shfl_xor(con[l], m, 64);
        }
        if (lane == 0) {
            #pragma unroll
            for (int l = 0; l < 16; ++l) s_wpart[wv][l] = con[l];
        }
        __syncthreads();

        const int p = it & 1;
        if (tid < 16) {
            float bs = 0.f;
            #pragma unroll
            for (int w = 0; w < 16; ++w) bs += s_wpart[w][tid];
            const unsigned long long v =
                ((unsigned long long)(unsigned)it << 32) |
                (unsigned long long)__float_as_uint(bs);
            __hip_atomic_store(&slab[(size_t)p * (NBLK2 * 16) + (size_t)blockIdx.x * 16 + tid],
                               v, __ATOMIC_RELAXED, __HIP_MEMORY_SCOPE_AGENT);
        }
        if (tid < NBLK2 * 16) {
            unsigned long long v;
            int spins = 0;
            do {
                v = __hip_atomic_load(&slab[(size_t)p * (NBLK2 * 16) + tid],
                                      __ATOMIC_RELAXED, __HIP_MEMORY_SCOPE_AGENT);
            } while ((unsigned)(v >> 32) != (unsigned)it && ++spins < (1 << 22));
            s_bpart[tid >> 4][tid & 15] = __uint_as_float((unsigned)(v & 0xffffffffull));
        }
        __syncthreads();

        if (tid < 16) {
            float tot = 0.f;
            #pragma unroll
            for (int b = 0; b < NBLK2; ++b) tot += s_bpart[b][tid];
            s_d1n[tid] = (1.f / (float)L_DIM) / (tot + 1e-8f);
        }
        __syncthreads();

        float esum = 0.f;
        #pragma unroll
        for (int l = 0; l < 16; ++l) {
            const float nv = s_d1n[l];
            esum += fabsf(d1[l] - nv);
            d1[l] = nv;
        }
        err = esum * (1.f / 16.f);
        ++it;
    } while (err > 1e-4f && it < 512);

    // fused finalize: top-2 of (d1*c)*d0n, softmax-gather (same op order as ref)
    float v1 = -__builtin_inff(), v2 = -__builtin_inff();
    float a1 = 0.f, a2 = 0.f;
    int   i1 = 0, i2 = 0;
    float ssum = 0.f;
    #pragma unroll
    for (int l = 0; l < 16; ++l) {
        ssum += c[l];
        const float nv = (d1[l] * c[l]) * d0n;
        if (nv > v1) { v2 = v1; i2 = i1; a2 = a1; v1 = nv; i1 = l; a1 = c[l]; }
        else if (nv > v2) { v2 = nv; i2 = l; a2 = c[l]; }
    }
    out[(size_t)t * 2 + 0] = a1 / ssum;
    out[(size_t)t * 2 + 1] = a2 / ssum;
    out[(size_t)2 * T_TOK + (size_t)t * 2 + 0] = (float)i1;
    out[(size_t)2 * T_TOK + (size_t)t * 2 + 1] = (float)i2;
}

extern "C" void kernel_launch(void* const* d_in, const int* in_sizes, int n_in,
                              void* d_out, int out_size, void* d_ws, size_t ws_size,
                              hipStream_t stream) {
    const float* x   = (const float*)d_in[0];
    const float* w1  = (const float*)d_in[1];
    const int*   tpe = (const int*)d_in[2];
    float* ws  = (float*)d_ws;
    float* out = (float*)d_out;

    // K1: logits partials (1024 blocks, 4 blocks/CU)
    k1a<<<dim3(128 * NSB), dim3(256), 0, stream>>>(x, w1, tpe, ws + WS_PB);

    // K2: pb-reduce + sinkhorn + finalize (cooperative for co-residency;
    // sync is the one-sided tagged slab, no grid.sync)
    {
        void* args[] = { (void*)&ws, (void*)&out };
        hipLaunchCooperativeKernel((void*)k_sinkhorn, dim3(NBLK2), dim3(BLK2),
                                   args, 0, stream);
    }
}

// Round 5
// 88.410 us; speedup vs baseline: 2.0231x; 2.0231x over previous
//
#include <hip/hip_runtime.h>

constexpr int T_TOK = 8192;
constexpr int H_DIM = 2048;
constexpr int E_NUM = 8;
constexpr int L_DIM = 16;

constexpr int NSB   = 8;     // h-slabs of 256
constexpr int NBLK2 = 8;     // sinkhorn blocks
constexpr int BLK2  = 1024;  // sinkhorn threads/block; NBLK2*BLK2 == T_TOK

// workspace layout (float offsets); slab first (8B aligned at 0)
constexpr size_t WS_SLAB = 0;                      // 2*NBLK2*16 u64 = 512 floats
constexpr size_t WS_PB   = 512;                    // NSB * T * 16 floats

// ---------------- Kernel 1: grouped logits partials ----------------
// 512 blocks = (tset 0..63)<<3 | (sb 0..7); block = 128 tokens x 256 h.
// Each lane owns 2 tokens (acc[2][16] = 32 VGPR) -> 8 FMA per ds_read_b128.
// w slab broadcast from LDS (wave-uniform addresses, conflict-free).
// launch_bounds(256,2): VGPR cap 256 -> NO spill (R4's (256,4) spilled).
__global__ __launch_bounds__(256, 2) void k1a(const float* __restrict__ x,
                                              const float* __restrict__ w1,
                                              const int* __restrict__ tpe,
                                              float* __restrict__ pb) {
    const int tid  = threadIdx.x;
    const int sb   = blockIdx.x & 7;
    const int tset = blockIdx.x >> 3;       // 0..63 (128 tokens each)
    const int wvi  = tid >> 6;              // wave 0..3 -> 64-h sub-window
    const int lane = tid & 63;
    const int h0   = sb * 256;

    // union LDS: phase 1 = w[256][16] (4096 f, 16 KB); phase 2 = red[4*128][17]
    __shared__ float smem[8704];

    // expert id (expert boundaries are multiples of the 128-token set here)
    int e = 0;
    {
        const int tok0 = tset * 128;
        int accum = 0;
        #pragma unroll
        for (int i = 0; i < E_NUM - 1; ++i) {
            accum += tpe[i];
            e += (tok0 >= accum) ? 1 : 0;
        }
    }
    const int e0 = __builtin_amdgcn_readfirstlane(e);

    // ---- stage w[e][h0..h0+256)[16] -> LDS linear (proven R3 layout) ----
    {
        const float4* wsrc =
            reinterpret_cast<const float4*>(w1 + ((size_t)e0 * H_DIM + h0) * L_DIM);
        float4* s4 = reinterpret_cast<float4*>(smem);
        #pragma unroll
        for (int i = 0; i < 4; ++i)
            s4[i * 256 + tid] = wsrc[i * 256 + tid];
    }

    // lane's two tokens; 16-float4 window at this wave's 64-h sub-window
    const int t0 = tset * 128 + lane;
    const float4* __restrict__ xp0 =
        reinterpret_cast<const float4*>(x) + (size_t)t0 * (H_DIM / 4) + (h0 >> 2) + wvi * 16;
    const float4* __restrict__ xp1 = xp0 + (size_t)64 * (H_DIM / 4);

    float acc[2][16];
    #pragma unroll
    for (int r = 0; r < 2; ++r)
        #pragma unroll
        for (int l = 0; l < 16; ++l) acc[r][l] = 0.f;

    // rolling prefetch: 4 float4 per token per group, 4 groups
    float4 xa[4], xb[4], xna[4], xnb[4];
    #pragma unroll
    for (int j = 0; j < 4; ++j) { xa[j] = xp0[j]; xb[j] = xp1[j]; }

    __syncthreads();   // w ready

    #pragma unroll
    for (int g = 0; g < 4; ++g) {
        if (g < 3) {
            #pragma unroll
            for (int j = 0; j < 4; ++j) {
                xna[j] = xp0[(g + 1) * 4 + j];
                xnb[j] = xp1[(g + 1) * 4 + j];
            }
        }
        #pragma unroll
        for (int j = 0; j < 4; ++j) {
            const int hl = wvi * 64 + (g * 4 + j) * 4;   // h_local of this float4
            const float xs0[4] = {xa[j].x, xa[j].y, xa[j].z, xa[j].w};
            const float xs1[4] = {xb[j].x, xb[j].y, xb[j].z, xb[j].w};
            #pragma unroll
            for (int hh = 0; hh < 4; ++hh) {
                // wave-uniform LDS address -> broadcast, conflict-free
                const float4* wrow = reinterpret_cast<const float4*>(&smem[(hl + hh) * 16]);
                const float v0 = xs0[hh], v1 = xs1[hh];
                #pragma unroll
                for (int q = 0; q < 4; ++q) {
                    const float4 w4 = wrow[q];
                    acc[0][q * 4 + 0] += v0 * w4.x;
                    acc[0][q * 4 + 1] += v0 * w4.y;
                    acc[0][q * 4 + 2] += v0 * w4.z;
                    acc[0][q * 4 + 3] += v0 * w4.w;
                    acc[1][q * 4 + 0] += v1 * w4.x;
                    acc[1][q * 4 + 1] += v1 * w4.y;
                    acc[1][q * 4 + 2] += v1 * w4.z;
                    acc[1][q * 4 + 3] += v1 * w4.w;
                }
            }
        }
        #pragma unroll
        for (int j = 0; j < 4; ++j) { xa[j] = xna[j]; xb[j] = xnb[j]; }
    }

    // ---- cross-wave reduce: red[wvi*128 + tok][17] (17 odd -> conflict-free) ----
    __syncthreads();   // done reading w; reuse smem
    #pragma unroll
    for (int r = 0; r < 2; ++r) {
        const int tok = r * 64 + lane;
        #pragma unroll
        for (int l = 0; l < 16; ++l)
            smem[(wvi * 128 + tok) * 17 + l] = acc[r][l];
    }
    __syncthreads();

    // 128 tok * 16 l = 2048 outputs; 256 threads do 8 each, coalesced store
    #pragma unroll
    for (int i = 0; i < 8; ++i) {
        const int p   = i * 256 + tid;
        const int tok = p >> 4;
        const int l   = p & 15;
        const float s = smem[(0 * 128 + tok) * 17 + l] + smem[(1 * 128 + tok) * 17 + l]
                      + smem[(2 * 128 + tok) * 17 + l] + smem[(3 * 128 + tok) * 17 + l];
        pb[(size_t)sb * (T_TOK * L_DIM) + (size_t)tset * 2048 + p] = s;
    }
}

// ---------------- Kernel 2: Sinkhorn + fused finalize ----------------
// 8 blocks x 1024 thr (one row/thread, c[16] in VGPRs). One-sided sync:
// per iteration each block publishes 16 col-partials as {tag,f32} u64
// relaxed agent-atomics (parity double-buffered); 128 threads spin, one
// entry each. write(it+1) implies read(it) done, so 2-ahead overwrite is
// impossible. Deterministic: fixed-order sums, bitwise-stable replays.
__global__ __launch_bounds__(1024) void k_sinkhorn(float* __restrict__ ws,
                                                   float* __restrict__ out) {
    unsigned long long* slab = reinterpret_cast<unsigned long long*>(ws + WS_SLAB);
    const float* pb = ws + WS_PB;

    const int tid  = threadIdx.x;
    const int t    = blockIdx.x * BLK2 + tid;   // row id
    const int wv   = tid >> 6;                  // 0..15
    const int lane = tid & 63;

    // fused: sum the 8 h-slab partials, exp -> c[]
    float c[16];
    {
        float4 a0 = {0,0,0,0}, a1 = {0,0,0,0}, a2 = {0,0,0,0}, a3 = {0,0,0,0};
        #pragma unroll
        for (int b = 0; b < NSB; ++b) {
            const float4* pr =
                reinterpret_cast<const float4*>(pb + (size_t)b * (T_TOK * L_DIM) + (size_t)t * 16);
            const float4 p0 = pr[0], p1 = pr[1], p2 = pr[2], p3 = pr[3];
            a0.x += p0.x; a0.y += p0.y; a0.z += p0.z; a0.w += p0.w;
            a1.x += p1.x; a1.y += p1.y; a1.z += p1.z; a1.w += p1.w;
            a2.x += p2.x; a2.y += p2.y; a2.z += p2.z; a2.w += p2.w;
            a3.x += p3.x; a3.y += p3.y; a3.z += p3.z; a3.w += p3.w;
        }
        const float sv[16] = {a0.x, a0.y, a0.z, a0.w, a1.x, a1.y, a1.z, a1.w,
                              a2.x, a2.y, a2.z, a2.w, a3.x, a3.y, a3.z, a3.w};
        #pragma unroll
        for (int l = 0; l < 16; ++l) c[l] = expf(sv[l]);
    }

    float d1[16];
    #pragma unroll
    for (int l = 0; l < 16; ++l) d1[l] = 1.f;

    __shared__ float s_wpart[16][16];
    __shared__ float s_bpart[NBLK2][16];
    __shared__ float s_d1n[16];

    float d0n = 0.f;
    float err = 1e9f;
    int it = 0;

    do {
        float s = 0.f;
        #pragma unroll
        for (int l = 0; l < 16; ++l) s += c[l] * d1[l];
        d0n = (1.f / (float)T_TOK) / (s + 1e-8f);

        float con[16];
        #pragma unroll
        for (int l = 0; l < 16; ++l) con[l] = d0n * c[l];
        #pragma unroll
        for (int m = 1; m < 64; m <<= 1) {
            #pragma unroll
            for (int l = 0; l < 16; ++l) con[l] += __shfl_xor(con[l], m, 64);
        }
        if (lane == 0) {
            #pragma unroll
            for (int l = 0; l < 16; ++l) s_wpart[wv][l] = con[l];
        }
        __syncthreads();

        const int p = it & 1;
        if (tid < 16) {
            float bs = 0.f;
            #pragma unroll
            for (int w = 0; w < 16; ++w) bs += s_wpart[w][tid];
            const unsigned long long v =
                ((unsigned long long)(unsigned)it << 32) |
                (unsigned long long)__float_as_uint(bs);
            __hip_atomic_store(&slab[(size_t)p * (NBLK2 * 16) + (size_t)blockIdx.x * 16 + tid],
                               v, __ATOMIC_RELAXED, __HIP_MEMORY_SCOPE_AGENT);
        }
        if (tid < NBLK2 * 16) {
            unsigned long long v;
            int spins = 0;
            do {
                v = __hip_atomic_load(&slab[(size_t)p * (NBLK2 * 16) + tid],
                                      __ATOMIC_RELAXED, __HIP_MEMORY_SCOPE_AGENT);
            } while ((unsigned)(v >> 32) != (unsigned)it && ++spins < (1 << 22));
            s_bpart[tid >> 4][tid & 15] = __uint_as_float((unsigned)(v & 0xffffffffull));
        }
        __syncthreads();

        if (tid < 16) {
            float tot = 0.f;
            #pragma unroll
            for (int b = 0; b < NBLK2; ++b) tot += s_bpart[b][tid];
            s_d1n[tid] = (1.f / (float)L_DIM) / (tot + 1e-8f);
        }
        __syncthreads();

        float esum = 0.f;
        #pragma unroll
        for (int l = 0; l < 16; ++l) {
            const float nv = s_d1n[l];
            esum += fabsf(d1[l] - nv);
            d1[l] = nv;
        }
        err = esum * (1.f / 16.f);
        ++it;
    } while (err > 1e-4f && it < 512);

    // fused finalize: top-2 of (d1*c)*d0n, softmax-gather (same op order as ref)
    float v1 = -__builtin_inff(), v2 = -__builtin_inff();
    float a1 = 0.f, a2 = 0.f;
    int   i1 = 0, i2 = 0;
    float ssum = 0.f;
    #pragma unroll
    for (int l = 0; l < 16; ++l) {
        ssum += c[l];
        const float nv = (d1[l] * c[l]) * d0n;
        if (nv > v1) { v2 = v1; i2 = i1; a2 = a1; v1 = nv; i1 = l; a1 = c[l]; }
        else if (nv > v2) { v2 = nv; i2 = l; a2 = c[l]; }
    }
    out[(size_t)t * 2 + 0] = a1 / ssum;
    out[(size_t)t * 2 + 1] = a2 / ssum;
    out[(size_t)2 * T_TOK + (size_t)t * 2 + 0] = (float)i1;
    out[(size_t)2 * T_TOK + (size_t)t * 2 + 1] = (float)i2;
}

extern "C" void kernel_launch(void* const* d_in, const int* in_sizes, int n_in,
                              void* d_out, int out_size, void* d_ws, size_t ws_size,
                              hipStream_t stream) {
    const float* x   = (const float*)d_in[0];
    const float* w1  = (const float*)d_in[1];
    const int*   tpe = (const int*)d_in[2];
    float* ws  = (float*)d_ws;
    float* out = (float*)d_out;

    // K1: logits partials (512 blocks, 2 blocks/CU)
    k1a<<<dim3(64 * NSB), dim3(256), 0, stream>>>(x, w1, tpe, ws + WS_PB);

    // K2: pb-reduce + sinkhorn + finalize (cooperative for co-residency;
    // sync is the one-sided tagged slab, no grid.sync)
    {
        void* args[] = { (void*)&ws, (void*)&out };
        hipLaunchCooperativeKernel((void*)k_sinkhorn, dim3(NBLK2), dim3(BLK2),
                                   args, 0, stream);
    }
}

// Round 6
// 79.005 us; speedup vs baseline: 2.2639x; 1.1190x over previous
//
#include <hip/hip_runtime.h>

constexpr int T_TOK = 8192;
constexpr int H_DIM = 2048;
constexpr int E_NUM = 8;
constexpr int L_DIM = 16;

constexpr int KSB   = 16;    // h-slabs of 128 (pb partial slabs)
constexpr int NBLK2 = 8;     // sinkhorn blocks
constexpr int BLK2  = 1024;  // sinkhorn threads/block; NBLK2*BLK2 == T_TOK

// workspace layout (float offsets); slab first (8B aligned at 0)
constexpr size_t WS_SLAB = 0;                      // 2*NBLK2*16 u64 = 512 floats
constexpr size_t WS_PB   = 512;                    // KSB * T * 16 floats (8.4 MB)

// ---------------- Kernel 1: grouped logits partials (tile GEMM) ----------------
// 2048 blocks = (tset 0..127)<<4 | (sb 0..15). Tile: 64 tokens x 16 L x 128 h.
// Both operands staged in LDS with COALESCED global loads (fixes the
// lane-owns-token gather that kept k1a TA/latency-bound at 54-60us).
// Thread (tokg,lg,ksub) = acc[4 tok][4 l] over ksub-interleaved k-slice:
// per 4-h step: 4+4 ds_read_b128 (immediate offsets, <=2-way banks) -> 64 FMA.
__global__ __launch_bounds__(256) void k1a(const float* __restrict__ x,
                                           const float* __restrict__ w1,
                                           const int* __restrict__ tpe,
                                           float* __restrict__ pb) {
    const int tid  = threadIdx.x;
    const int sb   = blockIdx.x & 15;
    const int tset = blockIdx.x >> 4;
    const int tokg = tid >> 4;          // 0..15
    const int lg   = (tid >> 2) & 3;    // 0..3
    const int ksub = tid & 3;           // 0..3
    const int h0   = sb * 128;

    // LDS: xbuf[64][132] (33792 f? bytes: 64*132*4=33792) + wbuf[128][20] (10240 B)
    // union: red[4][64][17] (17408 B) overlays xbuf after compute.
    __shared__ float xbuf[64 * 132];
    __shared__ float wbuf[128 * 20];

    // expert id (64-token tile lies within one expert group; boundaries @1024)
    int e = 0;
    {
        const int tok0 = tset * 64;
        int accum = 0;
        #pragma unroll
        for (int i = 0; i < E_NUM - 1; ++i) {
            accum += tpe[i];
            e += (tok0 >= accum) ? 1 : 0;
        }
    }
    const int e0 = __builtin_amdgcn_readfirstlane(e);

    // ---- stage w[e][h0..h0+128)[16] -> wbuf[h][20] (pad 20: <=2-way banks) ----
    {
        const float4* wsrc =
            reinterpret_cast<const float4*>(w1 + ((size_t)e0 * H_DIM + h0) * L_DIM);
        #pragma unroll
        for (int it = 0; it < 2; ++it) {
            const int idx = it * 256 + tid;          // float4 id 0..511
            const float4 v = wsrc[idx];
            const int h  = idx >> 2;
            const int l0 = (idx & 3) * 4;
            *reinterpret_cast<float4*>(&wbuf[h * 20 + l0]) = v;
        }
    }

    // ---- stage x[tset*64..+64)[h0..h0+128) -> xbuf[row][132] coalesced ----
    {
        const int row = tid >> 2;                    // 0..63
        const int c4  = tid & 3;
        const float* xrow = x + (size_t)(tset * 64 + row) * H_DIM + h0;
        float4 v[8];
        #pragma unroll
        for (int j = 0; j < 8; ++j)
            v[j] = *reinterpret_cast<const float4*>(xrow + (c4 + 4 * j) * 4);
        #pragma unroll
        for (int j = 0; j < 8; ++j)
            *reinterpret_cast<float4*>(&xbuf[row * 132 + (c4 + 4 * j) * 4]) = v[j];
    }

    __syncthreads();

    // ---- compute: acc[4 tok][4 l] over k-slice {16s + 4ksub + j} ----
    float acc[4][4];
    #pragma unroll
    for (int r = 0; r < 4; ++r)
        #pragma unroll
        for (int q = 0; q < 4; ++q) acc[r][q] = 0.f;

    // base addresses (bytes folded by compiler; offsets are compile-time)
    const float* xb[4];
    #pragma unroll
    for (int r = 0; r < 4; ++r)
        xb[r] = &xbuf[(4 * tokg + r) * 132 + 4 * ksub];
    const float* wb = &wbuf[(4 * ksub) * 20 + 4 * lg];

    #pragma unroll
    for (int s = 0; s < 8; ++s) {
        float4 xr[4], wj[4];
        #pragma unroll
        for (int r = 0; r < 4; ++r)
            xr[r] = *reinterpret_cast<const float4*>(xb[r] + 16 * s);   // offset:64s
        #pragma unroll
        for (int j = 0; j < 4; ++j)
            wj[j] = *reinterpret_cast<const float4*>(wb + 320 * s + 20 * j);
        #pragma unroll
        for (int r = 0; r < 4; ++r) {
            const float xs[4] = {xr[r].x, xr[r].y, xr[r].z, xr[r].w};
            #pragma unroll
            for (int j = 0; j < 4; ++j) {
                acc[r][0] += xs[j] * wj[j].x;
                acc[r][1] += xs[j] * wj[j].y;
                acc[r][2] += xs[j] * wj[j].z;
                acc[r][3] += xs[j] * wj[j].w;
            }
        }
    }

    // ---- reduce over ksub via LDS overlay, write pb coalesced ----
    __syncthreads();   // done reading xbuf; overlay red[4][64][17]
    float* red = xbuf;
    #pragma unroll
    for (int r = 0; r < 4; ++r)
        #pragma unroll
        for (int q = 0; q < 4; ++q)
            red[ksub * 1088 + (4 * tokg + r) * 17 + 4 * lg + q] = acc[r][q];
    __syncthreads();

    // 1024 outputs; thread does 4 contiguous -> one float4 store
    {
        float4 o;
        float* op = &o.x;
        #pragma unroll
        for (int i = 0; i < 4; ++i) {
            const int p   = 4 * tid + i;
            const int tok = p >> 4;
            const int l   = p & 15;
            op[i] = red[0 * 1088 + tok * 17 + l] + red[1 * 1088 + tok * 17 + l]
                  + red[2 * 1088 + tok * 17 + l] + red[3 * 1088 + tok * 17 + l];
        }
        *reinterpret_cast<float4*>(
            &pb[(size_t)sb * (T_TOK * L_DIM) + (size_t)tset * 1024 + 4 * tid]) = o;
    }
}

// ---------------- Kernel 2: Sinkhorn + fused finalize ----------------
// 8 blocks x 1024 thr (one row/thread, c[16] in VGPRs). One-sided sync:
// per iteration each block publishes 16 col-partials as {tag,f32} u64
// relaxed agent-atomics (parity double-buffered); 128 threads spin, one
// entry each. write(it+1) implies read(it) done, so 2-ahead overwrite is
// impossible. Deterministic: fixed-order sums, bitwise-stable replays.
__global__ __launch_bounds__(1024) void k_sinkhorn(float* __restrict__ ws,
                                                   float* __restrict__ out) {
    unsigned long long* slab = reinterpret_cast<unsigned long long*>(ws + WS_SLAB);
    const float* pb = ws + WS_PB;

    const int tid  = threadIdx.x;
    const int t    = blockIdx.x * BLK2 + tid;   // row id
    const int wv   = tid >> 6;                  // 0..15
    const int lane = tid & 63;

    // fused: sum the 16 h-slab partials, exp -> c[]
    float c[16];
    {
        float4 a0 = {0,0,0,0}, a1 = {0,0,0,0}, a2 = {0,0,0,0}, a3 = {0,0,0,0};
        #pragma unroll
        for (int b = 0; b < KSB; ++b) {
            const float4* pr =
                reinterpret_cast<const float4*>(pb + (size_t)b * (T_TOK * L_DIM) + (size_t)t * 16);
            const float4 p0 = pr[0], p1 = pr[1], p2 = pr[2], p3 = pr[3];
            a0.x += p0.x; a0.y += p0.y; a0.z += p0.z; a0.w += p0.w;
            a1.x += p1.x; a1.y += p1.y; a1.z += p1.z; a1.w += p1.w;
            a2.x += p2.x; a2.y += p2.y; a2.z += p2.z; a2.w += p2.w;
            a3.x += p3.x; a3.y += p3.y; a3.z += p3.z; a3.w += p3.w;
        }
        const float sv[16] = {a0.x, a0.y, a0.z, a0.w, a1.x, a1.y, a1.z, a1.w,
                              a2.x, a2.y, a2.z, a2.w, a3.x, a3.y, a3.z, a3.w};
        #pragma unroll
        for (int l = 0; l < 16; ++l) c[l] = expf(sv[l]);
    }

    float d1[16];
    #pragma unroll
    for (int l = 0; l < 16; ++l) d1[l] = 1.f;

    __shared__ float s_wpart[16][16];
    __shared__ float s_bpart[NBLK2][16];
    __shared__ float s_d1n[16];

    float d0n = 0.f;
    float err = 1e9f;
    int it = 0;

    do {
        float s = 0.f;
        #pragma unroll
        for (int l = 0; l < 16; ++l) s += c[l] * d1[l];
        d0n = (1.f / (float)T_TOK) / (s + 1e-8f);

        float con[16];
        #pragma unroll
        for (int l = 0; l < 16; ++l) con[l] = d0n * c[l];
        #pragma unroll
        for (int m = 1; m < 64; m <<= 1) {
            #pragma unroll
            for (int l = 0; l < 16; ++l) con[l] += __shfl_xor(con[l], m, 64);
        }
        if (lane == 0) {
            #pragma unroll
            for (int l = 0; l < 16; ++l) s_wpart[wv][l] = con[l];
        }
        __syncthreads();

        const int p = it & 1;
        if (tid < 16) {
            float bs = 0.f;
            #pragma unroll
            for (int w = 0; w < 16; ++w) bs += s_wpart[w][tid];
            const unsigned long long v =
                ((unsigned long long)(unsigned)it << 32) |
                (unsigned long long)__float_as_uint(bs);
            __hip_atomic_store(&slab[(size_t)p * (NBLK2 * 16) + (size_t)blockIdx.x * 16 + tid],
                               v, __ATOMIC_RELAXED, __HIP_MEMORY_SCOPE_AGENT);
        }
        if (tid < NBLK2 * 16) {
            unsigned long long v;
            int spins = 0;
            do {
                v = __hip_atomic_load(&slab[(size_t)p * (NBLK2 * 16) + tid],
                                      __ATOMIC_RELAXED, __HIP_MEMORY_SCOPE_AGENT);
            } while ((unsigned)(v >> 32) != (unsigned)it && ++spins < (1 << 22));
            s_bpart[tid >> 4][tid & 15] = __uint_as_float((unsigned)(v & 0xffffffffull));
        }
        __syncthreads();

        if (tid < 16) {
            float tot = 0.f;
            #pragma unroll
            for (int b = 0; b < NBLK2; ++b) tot += s_bpart[b][tid];
            s_d1n[tid] = (1.f / (float)L_DIM) / (tot + 1e-8f);
        }
        __syncthreads();

        float esum = 0.f;
        #pragma unroll
        for (int l = 0; l < 16; ++l) {
            const float nv = s_d1n[l];
            esum += fabsf(d1[l] - nv);
            d1[l] = nv;
        }
        err = esum * (1.f / 16.f);
        ++it;
    } while (err > 1e-4f && it < 512);

    // fused finalize: top-2 of (d1*c)*d0n, softmax-gather (same op order as ref)
    float v1 = -__builtin_inff(), v2 = -__builtin_inff();
    float a1 = 0.f, a2 = 0.f;
    int   i1 = 0, i2 = 0;
    float ssum = 0.f;
    #pragma unroll
    for (int l = 0; l < 16; ++l) {
        ssum += c[l];
        const float nv = (d1[l] * c[l]) * d0n;
        if (nv > v1) { v2 = v1; i2 = i1; a2 = a1; v1 = nv; i1 = l; a1 = c[l]; }
        else if (nv > v2) { v2 = nv; i2 = l; a2 = c[l]; }
    }
    out[(size_t)t * 2 + 0] = a1 / ssum;
    out[(size_t)t * 2 + 1] = a2 / ssum;
    out[(size_t)2 * T_TOK + (size_t)t * 2 + 0] = (float)i1;
    out[(size_t)2 * T_TOK + (size_t)t * 2 + 1] = (float)i2;
}

extern "C" void kernel_launch(void* const* d_in, const int* in_sizes, int n_in,
                              void* d_out, int out_size, void* d_ws, size_t ws_size,
                              hipStream_t stream) {
    const float* x   = (const float*)d_in[0];
    const float* w1  = (const float*)d_in[1];
    const int*   tpe = (const int*)d_in[2];
    float* ws  = (float*)d_ws;
    float* out = (float*)d_out;

    // K1: tile-GEMM logits partials (2048 blocks, 4 blocks/CU, 16 waves/CU)
    k1a<<<dim3(128 * KSB), dim3(256), 0, stream>>>(x, w1, tpe, ws + WS_PB);

    // K2: pb-reduce + sinkhorn + finalize (cooperative for co-residency;
    // sync is the one-sided tagged slab, no grid.sync)
    {
        void* args[] = { (void*)&ws, (void*)&out };
        hipLaunchCooperativeKernel((void*)k_sinkhorn, dim3(NBLK2), dim3(BLK2),
                                   args, 0, stream);
    }
}

// Round 7
// 66.451 us; speedup vs baseline: 2.6916x; 1.1889x over previous
//
#include <hip/hip_runtime.h>

constexpr int T_TOK = 8192;
constexpr int H_DIM = 2048;
constexpr int E_NUM = 8;
constexpr int L_DIM = 16;

constexpr int KSB   = 16;    // h-slabs of 128
constexpr int NBLK2 = 8;     // sinkhorn blocks
constexpr int BLK2  = 256;   // sinkhorn threads/block; 8*256*4 rows == T_TOK

// workspace layout (float offsets); slab first (8B aligned at 0)
constexpr size_t WS_SLAB = 0;                      // 2*NBLK2*16 u64 = 512 floats
constexpr size_t WS_PB   = 512;                    // KSB * 16 * T floats (8.39 MB)

// ---------------- Kernel 1: grouped logits partials (tile GEMM) ----------------
// 2048 blocks = (tset 0..127)<<4 | (sb 0..15). Tile: 64 tokens x 16 L x 128 h.
// x-tile staged with BOTH-SIDES XOR swizzle (G21): LDS writes are lane-linear
// (conflict-free ds_write_b128), the global source is pre-swizzled per lane
// (within-row 16B-chunk permute -> same cache lines, coalescing unchanged),
// reads apply the same involution -> 2-way banks (free). Fixes R6's
// 4-8-way conflicted x reads (64 b128/thread = the LDS-pipe hot path).
// Partials written TRANSPOSED pbT[sb][l][t] so k2's prologue coalesces.
__global__ __launch_bounds__(256) void k1a(const float* __restrict__ x,
                                           const float* __restrict__ w1,
                                           const int* __restrict__ tpe,
                                           float* __restrict__ pbT) {
    const int tid  = threadIdx.x;
    const int sb   = blockIdx.x & 15;
    const int tset = blockIdx.x >> 4;
    const int tokg = tid >> 4;          // 0..15
    const int lg   = (tid >> 2) & 3;    // 0..3
    const int ksub = tid & 3;           // 0..3
    const int h0   = sb * 128;

    __shared__ float xbuf[8192];        // [64 rows][32 f4-chunks] swizzled
    __shared__ float wbuf[128 * 20];    // [h][20] pad: <=2-way on reads

    // expert id (64-token tile lies within one expert group; boundaries @1024)
    int e = 0;
    {
        const int tok0 = tset * 64;
        int accum = 0;
        #pragma unroll
        for (int i = 0; i < E_NUM - 1; ++i) {
            accum += tpe[i];
            e += (tok0 >= accum) ? 1 : 0;
        }
    }
    const int e0 = __builtin_amdgcn_readfirstlane(e);

    // ---- issue w loads (2 f4/thread) and x loads (8 f4/thread, swizzled src) ----
    const float4* wsrc =
        reinterpret_cast<const float4*>(w1 + ((size_t)e0 * H_DIM + h0) * L_DIM);
    const float4 wv0 = wsrc[tid];
    const float4 wv1 = wsrc[256 + tid];

    float4 xv[8];
    #pragma unroll
    for (int k = 0; k < 8; ++k) {
        const int slot = tid + 256 * k;                  // linear f4 slot 0..2047
        const int row  = slot >> 5;                      // 0..63
        const int pc   = slot & 31;                      // physical chunk
        const int lc   = pc ^ (((row >> 2) & 3) << 1);   // logical chunk (involution)
        xv[k] = *reinterpret_cast<const float4*>(
            x + (size_t)(tset * 64 + row) * H_DIM + h0 + 4 * lc);
    }

    // ---- LDS writes: w padded, x lane-linear (conflict-free) ----
    {
        const int h  = tid >> 2;
        const int l0 = (tid & 3) * 4;
        *reinterpret_cast<float4*>(&wbuf[h * 20 + l0])        = wv0;
        *reinterpret_cast<float4*>(&wbuf[(64 + h) * 20 + l0]) = wv1;
    }
    #pragma unroll
    for (int k = 0; k < 8; ++k)
        *reinterpret_cast<float4*>(&xbuf[(tid + 256 * k) * 4]) = xv[k];

    __syncthreads();

    // ---- compute: acc[4 tok][4 l]; x read offset = 4*kk + 16*(s^tb) ----
    float acc[4][4];
    #pragma unroll
    for (int r = 0; r < 4; ++r)
        #pragma unroll
        for (int q = 0; q < 4; ++q) acc[r][q] = 0.f;

    const int tb = (tokg >> 1) & 1;
    const int kk = ksub ^ ((tokg & 1) << 1);
    const float* xrs[4];
    #pragma unroll
    for (int r = 0; r < 4; ++r)
        xrs[r] = &xbuf[(4 * tokg + r) * 128 + 4 * kk];
    const float* wb = &wbuf[(4 * ksub) * 20 + 4 * lg];

    #pragma unroll
    for (int s = 0; s < 8; ++s) {
        const int xo = ((s ^ tb) << 4);                  // (s^tb)*16 floats
        float4 xr[4], wj[4];
        #pragma unroll
        for (int r = 0; r < 4; ++r)
            xr[r] = *reinterpret_cast<const float4*>(xrs[r] + xo);
        #pragma unroll
        for (int j = 0; j < 4; ++j)
            wj[j] = *reinterpret_cast<const float4*>(wb + 320 * s + 20 * j);
        #pragma unroll
        for (int r = 0; r < 4; ++r) {
            const float xs[4] = {xr[r].x, xr[r].y, xr[r].z, xr[r].w};
            #pragma unroll
            for (int j = 0; j < 4; ++j) {
                acc[r][0] += xs[j] * wj[j].x;
                acc[r][1] += xs[j] * wj[j].y;
                acc[r][2] += xs[j] * wj[j].z;
                acc[r][3] += xs[j] * wj[j].w;
            }
        }
    }

    // ---- reduce over ksub via LDS overlay ----
    __syncthreads();   // done reading xbuf; overlay red[4][64][17]
    float* red = xbuf;
    #pragma unroll
    for (int r = 0; r < 4; ++r)
        #pragma unroll
        for (int q = 0; q < 4; ++q)
            red[ksub * 1088 + (4 * tokg + r) * 17 + 4 * lg + q] = acc[r][q];
    __syncthreads();

    // ---- write pbT[sb][l][t] : thread owns (l = tid>>4, 4 rows at 4*(tid&15)) ----
    {
        const int l  = tid >> 4;
        const int cc = tid & 15;
        float4 o;
        float* op = &o.x;
        #pragma unroll
        for (int j = 0; j < 4; ++j) {
            const int tok = 4 * cc + j;
            op[j] = red[0 * 1088 + tok * 17 + l] + red[1 * 1088 + tok * 17 + l]
                  + red[2 * 1088 + tok * 17 + l] + red[3 * 1088 + tok * 17 + l];
        }
        *reinterpret_cast<float4*>(
            &pbT[((size_t)(sb * 16 + l) << 13) + tset * 64 + 4 * cc]) = o;
    }
}

// ---------------- Kernel 2: Sinkhorn + fused finalize ----------------
// 8 blocks x 256 thr, 4 contiguous rows/thread (c[4][16] in VGPRs).
// Prologue: coalesced pbT reads (16sb x 16l float4 per thread), exp.
// Per iter: dots+divs -> con[16] -> 6-step butterfly -> s_wpart -> sync ->
// 16 column-owners publish tagged u64, parallel-spin on 8 entries, write
// s_d1n -> sync. 2 barriers/iter (was 3), deterministic fixed-order sums.
__global__ __launch_bounds__(256) void k_sinkhorn(float* __restrict__ ws,
                                                  float* __restrict__ out) {
    unsigned long long* slab = reinterpret_cast<unsigned long long*>(ws + WS_SLAB);
    const float* pbT = ws + WS_PB;

    const int tid  = threadIdx.x;
    const int blk  = blockIdx.x;
    const int wv   = tid >> 6;                  // 0..3
    const int lane = tid & 63;

    // prologue: c[i][l] for rows blk*1024 + 4*tid + i
    float c[4][16];
    #pragma unroll
    for (int i = 0; i < 4; ++i)
        #pragma unroll
        for (int l = 0; l < 16; ++l) c[i][l] = 0.f;

    #pragma unroll
    for (int sb = 0; sb < KSB; ++sb) {
        #pragma unroll
        for (int l = 0; l < 16; ++l) {
            const float4 v = *reinterpret_cast<const float4*>(
                pbT + ((size_t)(sb * 16 + l) << 13) + blk * 1024 + 4 * tid);
            c[0][l] += v.x; c[1][l] += v.y; c[2][l] += v.z; c[3][l] += v.w;
        }
    }
    #pragma unroll
    for (int i = 0; i < 4; ++i)
        #pragma unroll
        for (int l = 0; l < 16; ++l) c[i][l] = expf(c[i][l]);

    float d1[16];
    #pragma unroll
    for (int l = 0; l < 16; ++l) d1[l] = 1.f;

    __shared__ float s_wpart[4][16];
    __shared__ float s_d1n[16];

    float d0n[4] = {0.f, 0.f, 0.f, 0.f};
    float err = 1e9f;
    int it = 0;

    do {
        // d0n per row
        #pragma unroll
        for (int i = 0; i < 4; ++i) {
            float s = 0.f;
            #pragma unroll
            for (int l = 0; l < 16; ++l) s += c[i][l] * d1[l];
            d0n[i] = (1.f / (float)T_TOK) / (s + 1e-8f);
        }

        // per-lane column partials over the 4 rows
        float con[16];
        #pragma unroll
        for (int l = 0; l < 16; ++l)
            con[l] = d0n[0] * c[0][l] + d0n[1] * c[1][l]
                   + d0n[2] * c[2][l] + d0n[3] * c[3][l];
        #pragma unroll
        for (int m = 1; m < 64; m <<= 1) {
            #pragma unroll
            for (int l = 0; l < 16; ++l) con[l] += __shfl_xor(con[l], m, 64);
        }
        if (lane == 0) {
            #pragma unroll
            for (int l = 0; l < 16; ++l) s_wpart[wv][l] = con[l];
        }
        __syncthreads();

        const int p = it & 1;
        if (tid < 16) {
            const float bs = s_wpart[0][tid] + s_wpart[1][tid]
                           + s_wpart[2][tid] + s_wpart[3][tid];
            const unsigned long long pv =
                ((unsigned long long)(unsigned)it << 32) |
                (unsigned long long)__float_as_uint(bs);
            __hip_atomic_store(&slab[(size_t)p * 128 + blk * 16 + tid],
                               pv, __ATOMIC_RELAXED, __HIP_MEMORY_SCOPE_AGENT);

            // parallel spin on the 8 blocks' entries for this column
            unsigned long long v[NBLK2];
            #pragma unroll
            for (int b = 0; b < NBLK2; ++b)
                v[b] = __hip_atomic_load(&slab[(size_t)p * 128 + b * 16 + tid],
                                         __ATOMIC_RELAXED, __HIP_MEMORY_SCOPE_AGENT);
            int guard = 0;
            bool ok;
            do {
                ok = true;
                #pragma unroll
                for (int b = 0; b < NBLK2; ++b) {
                    if ((unsigned)(v[b] >> 32) != (unsigned)it) {
                        ok = false;
                        v[b] = __hip_atomic_load(&slab[(size_t)p * 128 + b * 16 + tid],
                                                 __ATOMIC_RELAXED, __HIP_MEMORY_SCOPE_AGENT);
                    }
                }
            } while (!ok && ++guard < (1 << 20));

            float tot = 0.f;
            #pragma unroll
            for (int b = 0; b < NBLK2; ++b)
                tot += __uint_as_float((unsigned)(v[b] & 0xffffffffull));
            s_d1n[tid] = (1.f / (float)L_DIM) / (tot + 1e-8f);
        }
        __syncthreads();

        float esum = 0.f;
        #pragma unroll
        for (int l = 0; l < 16; ++l) {
            const float nv = s_d1n[l];
            esum += fabsf(d1[l] - nv);
            d1[l] = nv;
        }
        err = esum * (1.f / 16.f);
        ++it;
    } while (err > 1e-4f && it < 512);

    // fused finalize per row: top-2 of (d1*c)*d0n, softmax-gather (ref op order)
    #pragma unroll
    for (int i = 0; i < 4; ++i) {
        const int t = blk * 1024 + 4 * tid + i;
        float v1 = -__builtin_inff(), v2 = -__builtin_inff();
        float a1 = 0.f, a2 = 0.f;
        int   i1 = 0, i2 = 0;
        float ssum = 0.f;
        #pragma unroll
        for (int l = 0; l < 16; ++l) {
            ssum += c[i][l];
            const float nv = (d1[l] * c[i][l]) * d0n[i];
            if (nv > v1) { v2 = v1; i2 = i1; a2 = a1; v1 = nv; i1 = l; a1 = c[i][l]; }
            else if (nv > v2) { v2 = nv; i2 = l; a2 = c[i][l]; }
        }
        out[(size_t)t * 2 + 0] = a1 / ssum;
        out[(size_t)t * 2 + 1] = a2 / ssum;
        out[(size_t)2 * T_TOK + (size_t)t * 2 + 0] = (float)i1;
        out[(size_t)2 * T_TOK + (size_t)t * 2 + 1] = (float)i2;
    }
}

extern "C" void kernel_launch(void* const* d_in, const int* in_sizes, int n_in,
                              void* d_out, int out_size, void* d_ws, size_t ws_size,
                              hipStream_t stream) {
    const float* x   = (const float*)d_in[0];
    const float* w1  = (const float*)d_in[1];
    const int*   tpe = (const int*)d_in[2];
    float* ws  = (float*)d_ws;
    float* out = (float*)d_out;

    // K1: tile-GEMM logits partials, transposed output
    k1a<<<dim3(128 * KSB), dim3(256), 0, stream>>>(x, w1, tpe, ws + WS_PB);

    // K2: coalesced pbT prologue + sinkhorn + finalize (cooperative for
    // co-residency; sync is the one-sided tagged slab, no grid.sync)
    {
        void* args[] = { (void*)&ws, (void*)&out };
        hipLaunchCooperativeKernel((void*)k_sinkhorn, dim3(NBLK2), dim3(BLK2),
                                   args, 0, stream);
    }
}

// Round 8
// 66.361 us; speedup vs baseline: 2.6953x; 1.0014x over previous
//
#include <hip/hip_runtime.h>

constexpr int T_TOK = 8192;
constexpr int H_DIM = 2048;
constexpr int E_NUM = 8;
constexpr int L_DIM = 16;

constexpr int KSB   = 16;    // h-slabs of 128
constexpr int NBLK2 = 8;     // sinkhorn blocks
constexpr int BLK2  = 256;   // sinkhorn threads/block; 8*256*4 rows == T_TOK

// workspace layout (float offsets); slab first (8B aligned at 0)
constexpr size_t WS_SLAB = 0;                      // 2*NBLK2*16 u64 = 512 floats
constexpr size_t WS_PB   = 512;                    // KSB * 16 * T floats (8.39 MB)

// ---------------- Kernel 1: grouped logits partials (tile GEMM) ----------------
// 2048 blocks = (tset 0..127)<<4 | (sb 0..15). Tile: 64 tokens x 16 L x 128 h.
// x-tile staged with BOTH-SIDES XOR swizzle (G21): LDS writes lane-linear
// (conflict-free ds_write_b128), global source pre-swizzled per lane,
// reads apply the same involution -> 2-way banks (free).
// Partials written TRANSPOSED pbT[sb][l][t] so k2's prologue coalesces.
__global__ __launch_bounds__(256) void k1a(const float* __restrict__ x,
                                           const float* __restrict__ w1,
                                           const int* __restrict__ tpe,
                                           float* __restrict__ pbT) {
    const int tid  = threadIdx.x;
    const int sb   = blockIdx.x & 15;
    const int tset = blockIdx.x >> 4;
    const int tokg = tid >> 4;          // 0..15
    const int lg   = (tid >> 2) & 3;    // 0..3
    const int ksub = tid & 3;           // 0..3
    const int h0   = sb * 128;

    __shared__ float xbuf[8192];        // [64 rows][32 f4-chunks] swizzled
    __shared__ float wbuf[128 * 20];    // [h][20] pad: <=2-way on reads

    // expert id (64-token tile lies within one expert group; boundaries @1024)
    int e = 0;
    {
        const int tok0 = tset * 64;
        int accum = 0;
        #pragma unroll
        for (int i = 0; i < E_NUM - 1; ++i) {
            accum += tpe[i];
            e += (tok0 >= accum) ? 1 : 0;
        }
    }
    const int e0 = __builtin_amdgcn_readfirstlane(e);

    // ---- issue w loads (2 f4/thread) and x loads (8 f4/thread, swizzled src) ----
    const float4* wsrc =
        reinterpret_cast<const float4*>(w1 + ((size_t)e0 * H_DIM + h0) * L_DIM);
    const float4 wv0 = wsrc[tid];
    const float4 wv1 = wsrc[256 + tid];

    float4 xv[8];
    #pragma unroll
    for (int k = 0; k < 8; ++k) {
        const int slot = tid + 256 * k;                  // linear f4 slot 0..2047
        const int row  = slot >> 5;                      // 0..63
        const int pc   = slot & 31;                      // physical chunk
        const int lc   = pc ^ (((row >> 2) & 3) << 1);   // logical chunk (involution)
        xv[k] = *reinterpret_cast<const float4*>(
            x + (size_t)(tset * 64 + row) * H_DIM + h0 + 4 * lc);
    }

    // ---- LDS writes: w padded, x lane-linear (conflict-free) ----
    {
        const int h  = tid >> 2;
        const int l0 = (tid & 3) * 4;
        *reinterpret_cast<float4*>(&wbuf[h * 20 + l0])        = wv0;
        *reinterpret_cast<float4*>(&wbuf[(64 + h) * 20 + l0]) = wv1;
    }
    #pragma unroll
    for (int k = 0; k < 8; ++k)
        *reinterpret_cast<float4*>(&xbuf[(tid + 256 * k) * 4]) = xv[k];

    __syncthreads();

    // ---- compute: acc[4 tok][4 l]; x read offset = 4*kk + 16*(s^tb) ----
    float acc[4][4];
    #pragma unroll
    for (int r = 0; r < 4; ++r)
        #pragma unroll
        for (int q = 0; q < 4; ++q) acc[r][q] = 0.f;

    const int tb = (tokg >> 1) & 1;
    const int kk = ksub ^ ((tokg & 1) << 1);
    const float* xrs[4];
    #pragma unroll
    for (int r = 0; r < 4; ++r)
        xrs[r] = &xbuf[(4 * tokg + r) * 128 + 4 * kk];
    const float* wb = &wbuf[(4 * ksub) * 20 + 4 * lg];

    #pragma unroll
    for (int s = 0; s < 8; ++s) {
        const int xo = ((s ^ tb) << 4);                  // (s^tb)*16 floats
        float4 xr[4], wj[4];
        #pragma unroll
        for (int r = 0; r < 4; ++r)
            xr[r] = *reinterpret_cast<const float4*>(xrs[r] + xo);
        #pragma unroll
        for (int j = 0; j < 4; ++j)
            wj[j] = *reinterpret_cast<const float4*>(wb + 320 * s + 20 * j);
        #pragma unroll
        for (int r = 0; r < 4; ++r) {
            const float xs[4] = {xr[r].x, xr[r].y, xr[r].z, xr[r].w};
            #pragma unroll
            for (int j = 0; j < 4; ++j) {
                acc[r][0] += xs[j] * wj[j].x;
                acc[r][1] += xs[j] * wj[j].y;
                acc[r][2] += xs[j] * wj[j].z;
                acc[r][3] += xs[j] * wj[j].w;
            }
        }
    }

    // ---- reduce over ksub via LDS overlay ----
    __syncthreads();   // done reading xbuf; overlay red[4][64][17]
    float* red = xbuf;
    #pragma unroll
    for (int r = 0; r < 4; ++r)
        #pragma unroll
        for (int q = 0; q < 4; ++q)
            red[ksub * 1088 + (4 * tokg + r) * 17 + 4 * lg + q] = acc[r][q];
    __syncthreads();

    // ---- write pbT[sb][l][t] : thread owns (l = tid>>4, 4 rows at 4*(tid&15)) ----
    {
        const int l  = tid >> 4;
        const int cc = tid & 15;
        float4 o;
        float* op = &o.x;
        #pragma unroll
        for (int j = 0; j < 4; ++j) {
            const int tok = 4 * cc + j;
            op[j] = red[0 * 1088 + tok * 17 + l] + red[1 * 1088 + tok * 17 + l]
                  + red[2 * 1088 + tok * 17 + l] + red[3 * 1088 + tok * 17 + l];
        }
        *reinterpret_cast<float4*>(
            &pbT[((size_t)(sb * 16 + l) << 13) + tset * 64 + 4 * cc]) = o;
    }
}

// ---------------- Kernel 2: Sinkhorn + fused finalize ----------------
// 8 blocks x 256 thr, 4 contiguous rows/thread (c[4][16] in VGPRs).
// Prologue: coalesced pbT reads. Per iter: dots -> butterfly -> s_wpart ->
// barrier -> 16 owners publish tagged u64; 128 lanes spin ONE entry each
// (lane-parallel LLC round trip — R7's 8-deep serial spin was the
// regression) -> s_bpart -> barrier -> 16 owners sum 8 + write s_d1n ->
// barrier. Deterministic fixed-order sums, bitwise-stable replays.
__global__ __launch_bounds__(256) void k_sinkhorn(float* __restrict__ ws,
                                                  float* __restrict__ out) {
    unsigned long long* slab = reinterpret_cast<unsigned long long*>(ws + WS_SLAB);
    const float* pbT = ws + WS_PB;

    const int tid  = threadIdx.x;
    const int blk  = blockIdx.x;
    const int wv   = tid >> 6;                  // 0..3
    const int lane = tid & 63;

    // prologue: c[i][l] for rows blk*1024 + 4*tid + i
    float c[4][16];
    #pragma unroll
    for (int i = 0; i < 4; ++i)
        #pragma unroll
        for (int l = 0; l < 16; ++l) c[i][l] = 0.f;

    #pragma unroll
    for (int sb = 0; sb < KSB; ++sb) {
        #pragma unroll
        for (int l = 0; l < 16; ++l) {
            const float4 v = *reinterpret_cast<const float4*>(
                pbT + ((size_t)(sb * 16 + l) << 13) + blk * 1024 + 4 * tid);
            c[0][l] += v.x; c[1][l] += v.y; c[2][l] += v.z; c[3][l] += v.w;
        }
    }
    #pragma unroll
    for (int i = 0; i < 4; ++i)
        #pragma unroll
        for (int l = 0; l < 16; ++l) c[i][l] = expf(c[i][l]);

    float d1[16];
    #pragma unroll
    for (int l = 0; l < 16; ++l) d1[l] = 1.f;

    __shared__ float s_wpart[4][16];
    __shared__ float s_bpart[NBLK2][16];
    __shared__ float s_d1n[16];

    float d0n[4] = {0.f, 0.f, 0.f, 0.f};
    float err = 1e9f;
    int it = 0;

    do {
        // d0n per row
        #pragma unroll
        for (int i = 0; i < 4; ++i) {
            float s = 0.f;
            #pragma unroll
            for (int l = 0; l < 16; ++l) s += c[i][l] * d1[l];
            d0n[i] = (1.f / (float)T_TOK) / (s + 1e-8f);
        }

        // per-lane column partials over the 4 rows
        float con[16];
        #pragma unroll
        for (int l = 0; l < 16; ++l)
            con[l] = d0n[0] * c[0][l] + d0n[1] * c[1][l]
                   + d0n[2] * c[2][l] + d0n[3] * c[3][l];
        #pragma unroll
        for (int m = 1; m < 64; m <<= 1) {
            #pragma unroll
            for (int l = 0; l < 16; ++l) con[l] += __shfl_xor(con[l], m, 64);
        }
        if (lane == 0) {
            #pragma unroll
            for (int l = 0; l < 16; ++l) s_wpart[wv][l] = con[l];
        }
        __syncthreads();

        const int p = it & 1;
        if (tid < 16) {
            const float bs = s_wpart[0][tid] + s_wpart[1][tid]
                           + s_wpart[2][tid] + s_wpart[3][tid];
            const unsigned long long pv =
                ((unsigned long long)(unsigned)it << 32) |
                (unsigned long long)__float_as_uint(bs);
            __hip_atomic_store(&slab[(size_t)p * 128 + blk * 16 + tid],
                               pv, __ATOMIC_RELAXED, __HIP_MEMORY_SCOPE_AGENT);
        }
        if (tid < NBLK2 * 16) {
            // lane-parallel spin: ONE entry per lane (one LLC latency/round)
            unsigned long long v;
            int spins = 0;
            do {
                v = __hip_atomic_load(&slab[(size_t)p * 128 + tid],
                                      __ATOMIC_RELAXED, __HIP_MEMORY_SCOPE_AGENT);
            } while ((unsigned)(v >> 32) != (unsigned)it && ++spins < (1 << 22));
            s_bpart[tid >> 4][tid & 15] = __uint_as_float((unsigned)(v & 0xffffffffull));
        }
        __syncthreads();

        if (tid < 16) {
            float tot = 0.f;
            #pragma unroll
            for (int b = 0; b < NBLK2; ++b) tot += s_bpart[b][tid];
            s_d1n[tid] = (1.f / (float)L_DIM) / (tot + 1e-8f);
        }
        __syncthreads();

        float esum = 0.f;
        #pragma unroll
        for (int l = 0; l < 16; ++l) {
            const float nv = s_d1n[l];
            esum += fabsf(d1[l] - nv);
            d1[l] = nv;
        }
        err = esum * (1.f / 16.f);
        ++it;
    } while (err > 1e-4f && it < 512);

    // fused finalize per row: top-2 of (d1*c)*d0n, softmax-gather (ref op order)
    #pragma unroll
    for (int i = 0; i < 4; ++i) {
        const int t = blk * 1024 + 4 * tid + i;
        float v1 = -__builtin_inff(), v2 = -__builtin_inff();
        float a1 = 0.f, a2 = 0.f;
        int   i1 = 0, i2 = 0;
        float ssum = 0.f;
        #pragma unroll
        for (int l = 0; l < 16; ++l) {
            ssum += c[i][l];
            const float nv = (d1[l] * c[i][l]) * d0n[i];
            if (nv > v1) { v2 = v1; i2 = i1; a2 = a1; v1 = nv; i1 = l; a1 = c[i][l]; }
            else if (nv > v2) { v2 = nv; i2 = l; a2 = c[i][l]; }
        }
        out[(size_t)t * 2 + 0] = a1 / ssum;
        out[(size_t)t * 2 + 1] = a2 / ssum;
        out[(size_t)2 * T_TOK + (size_t)t * 2 + 0] = (float)i1;
        out[(size_t)2 * T_TOK + (size_t)t * 2 + 1] = (float)i2;
    }
}

extern "C" void kernel_launch(void* const* d_in, const int* in_sizes, int n_in,
                              void* d_out, int out_size, void* d_ws, size_t ws_size,
                              hipStream_t stream) {
    const float* x   = (const float*)d_in[0];
    const float* w1  = (const float*)d_in[1];
    const int*   tpe = (const int*)d_in[2];
    float* ws  = (float*)d_ws;
    float* out = (float*)d_out;

    // K1: tile-GEMM logits partials, transposed output
    k1a<<<dim3(128 * KSB), dim3(256), 0, stream>>>(x, w1, tpe, ws + WS_PB);

    // K2: coalesced pbT prologue + sinkhorn + finalize (cooperative for
    // co-residency; sync is the one-sided tagged slab, no grid.sync)
    {
        void* args[] = { (void*)&ws, (void*)&out };
        hipLaunchCooperativeKernel((void*)k_sinkhorn, dim3(NBLK2), dim3(BLK2),
                                   args, 0, stream);
    }
}